// Round 6
// baseline (1421.412 us; speedup 1.0000x reference)
//
#include <hip/hip_runtime.h>

typedef _Float16 f16;
typedef _Float16 f16x2 __attribute__((ext_vector_type(2)));
typedef _Float16 f16x8 __attribute__((ext_vector_type(8)));
typedef float f32x4 __attribute__((ext_vector_type(4)));

namespace {

constexpr int kC = 16, kN = 8192, kH = 181, kOut = 3;
constexpr int kMB = 64;            // rows per block
constexpr int kKpad = 384;         // 12 ksteps * 32
constexpr int kNT = 48;            // n-tiles of 16 cols (Npad = 768)
constexpr int kKS = 12;            // k-steps of 32
constexpr int kRowB = kKpad * 2;   // 768 bytes per LDS activation row
constexpr float kOmega = 30.f, kS2 = 100.f;

constexpr size_t kWLayerStride = (size_t)kNT * kKS * 64 * 8;  // f16 elems per (c,layer)
constexpr size_t kWfOff = kWLayerStride * kC * 2;             // f16 elems
constexpr size_t kWfStride = (size_t)kKS * 64 * 8;

// XOR-swizzled LDS address (row stride 768B -> bank-degenerate without it).
__device__ __forceinline__ int swz(int row, int colb) {
  return row * kRowB + (colb ^ ((row & 7) << 4));
}

// Quad-lane exchange via DPP (VALU) instead of __shfl_xor (DS unit): the
// LDS pipe is the structural bottleneck, keep the transpose off it.
__device__ __forceinline__ float dpp_x1(float x) {  // lane ^ 1 within quad
  return __int_as_float(__builtin_amdgcn_mov_dpp(__float_as_int(x), 0xB1, 0xF, 0xF, true));
}
__device__ __forceinline__ float dpp_x2(float x) {  // lane ^ 2 within quad
  return __int_as_float(__builtin_amdgcn_mov_dpp(__float_as_int(x), 0x4E, 0xF, 0xF, true));
}

// 4x4 transpose across the 4-lane comp group (lane bits 0..1).
// In: v_j = C[row_off j][comp = lane&3]. Out: v_j = C[row_off = lane&3][comp j].
__device__ __forceinline__ void xpose4(float& v0, float& v1, float& v2, float& v3, int lane) {
  const bool b0 = lane & 1, b1 = lane & 2;
  float x0 = b0 ? v0 : v1;
  float x1 = b0 ? v2 : v3;
  x0 = dpp_x1(x0);
  x1 = dpp_x1(x1);
  if (b0) { v0 = x0; v2 = x1; } else { v1 = x0; v3 = x1; }
  float y0 = b1 ? v0 : v2;
  float y1 = b1 ? v1 : v3;
  y0 = dpp_x2(y0);
  y1 = dpp_x2(y1);
  if (b1) { v0 = y0; v1 = y1; } else { v2 = y0; v3 = y1; }
}

// ---- prep: pack hidden-layer complex weights into fp16 B-fragment order
// ws[c][L][nt][ks][lane][8]; K rows 2i/2i+1 = (x_re,x_im), N cols 4o+comp.
__global__ __launch_bounds__(768) void prep_hidden(
    const int* __restrict__ model_idx,
    const float* __restrict__ W1a, const float* __restrict__ W1b,
    const float* __restrict__ W2a, const float* __restrict__ W2b,
    f16* __restrict__ ws)
{
  __shared__ float s[kH][2][4][2];   // [i][branch][o_sub][reim]
  const int bid = blockIdx.x;
  const int c  = bid / (2 * kNT);
  const int L  = (bid / kNT) % 2;
  const int nt = bid % kNT;
  const int m  = model_idx[c];
  const float* Wa = (L == 0 ? W1a : W2a) + (size_t)m * kH * kH * 2;
  const float* Wb = (L == 0 ? W1b : W2b) + (size_t)m * kH * kH * 2;
  const int t = threadIdx.x;
  if (t < 2 * kH) {
    const int i = t >> 1, br = t & 1;
    const float* src = (br ? Wb : Wa) + ((size_t)i * kH + nt * 4) * 2;
#pragma unroll
    for (int e = 0; e < 8; ++e) {
      const int osub = e >> 1, reim = e & 1;
      s[i][br][osub][reim] = (nt * 4 + osub < kH) ? src[osub * 2 + reim] : 0.f;
    }
  }
  __syncthreads();
  const int ks = t >> 6, lane = t & 63;
  const int kg = lane >> 4, l15 = lane & 15;
  const int osub = l15 >> 2, comp = l15 & 3, br = comp >> 1;
  const int o = nt * 4 + osub;
  f16x8 v;
#pragma unroll
  for (int j = 0; j < 8; ++j) {
    const int k = ks * 32 + kg * 8 + j;
    float f = 0.f;
    if (k < 2 * kH && o < kH) {
      const int i = k >> 1, kodd = k & 1;
      const int reim = kodd ? (1 - (comp & 1)) : (comp & 1);
      f = s[i][br][osub][reim];
      if (kodd && !(comp & 1)) f = -f;   // -w_im for real-output cols
    }
    v[j] = (f16)f;
  }
  *(f16x8*)&ws[(((size_t)(c * 2 + L) * kNT + nt) * kKS + ks) * 512 + lane * 8] = v;
}

// ---- prep: final layer (real part): col j<3, k=2i -> wf_re, 2i+1 -> -wf_im
__global__ __launch_bounds__(768) void prep_final(
    const int* __restrict__ model_idx, const float* __restrict__ Wf,
    f16* __restrict__ ws)
{
  const int c = blockIdx.x;
  const int m = model_idx[c];
  const int t = threadIdx.x;
  const int ks = t >> 6, lane = t & 63;
  const int kg = lane >> 4, col = lane & 15;
  f16x8 v;
#pragma unroll
  for (int j = 0; j < 8; ++j) {
    const int k = ks * 32 + kg * 8 + j;
    float f = 0.f;
    if (k < 2 * kH && col < kOut) {
      const int i = k >> 1;
      const float* p = &Wf[(((size_t)m * kH + i) * kOut + col) * 2];
      f = (k & 1) ? -p[1] : p[0];
    }
    v[j] = (f16)f;
  }
  *(f16x8*)&ws[kWfOff + ((size_t)c * kKS + ks) * 512 + lane * 8] = v;
}

// ---- one hidden layer: GEMM (64 rows x 768 cols, K=384) + distributed Gabor
// activation. 16 waves; wave w owns ALL 64 rows (mt=0..3) x 3 n-tiles.
// B is read once per block (no row-group duplication -> L2 traffic halved),
// A re-read from LDS only once per (ks,mt) (48 KB/wave/layer).
__device__ __forceinline__ void hidden_gemm(
    const char* __restrict__ Xs, char* __restrict__ Xd,
    const f16x8* __restrict__ wl,
    const float* __restrict__ ba, const float* __restrict__ bb,
    int w, int lane)
{
  const int kg = lane >> 4, l15 = lane & 15;
  const int comp = l15 & 3, osub = l15 >> 2;
  const int nt0 = w * 3;
#pragma unroll 1
  for (int t = 0; t < 3; ++t) {
    const int nt = nt0 + t;
    const int q = nt * 4 + osub;
    const f16x8* bp = wl + (size_t)nt * kKS * 64 + lane;
    float bv = 0.f;
    if (q < kH) bv = ((comp & 2) ? bb : ba)[q * 2 + (comp & 1)];
    f32x4 acc[4] = {};
#pragma unroll
    for (int ks = 0; ks < kKS; ++ks) {
      const f16x8 b = bp[ks * 64];
#pragma unroll
      for (int mt = 0; mt < 4; ++mt) {
        const f16x8 a = *(const f16x8*)(Xs + swz(l15 + 16 * mt, ks * 64 + kg * 16));
        acc[mt] = __builtin_amdgcn_mfma_f32_16x16x32_f16(a, b, acc[mt], 0, 0, 0);
      }
    }
    // Bias (column property) then distributed activation: DPP 4x4 transpose
    // within the comp-group; every lane computes one (row, neuron) Gabor.
#pragma unroll
    for (int mt = 0; mt < 4; ++mt) {
      float v0 = acc[mt][0] + bv, v1 = acc[mt][1] + bv;
      float v2 = acc[mt][2] + bv, v3 = acc[mt][3] + bv;
      xpose4(v0, v1, v2, v3, lane);
      // v0..v3 = (la_re, la_im, lb_re, lb_im) at row_off = comp
      const float mag = kS2 * (v0 * v0 + v1 * v1 + v2 * v2 + v3 * v3);
      const float amp = __expf(fmaf(-kOmega, v1, -mag));
      const float ph  = kOmega * v0;
      f16x2 pv = {(f16)(amp * __cosf(ph)), (f16)(amp * __sinf(ph))};
      const int row = mt * 16 + kg * 4 + comp;
      *(f16x2*)(Xd + swz(row, q * 4)) = pv;
    }
  }
}

// 1024-thread block: makes <=128 VGPR a HARD schedulability constraint (the
// backend must fit 4 waves/SIMD), unlike the soft (256,4) hint that overshot
// to 132 and halved occupancy in round 5.
__global__ __launch_bounds__(1024) void wire_main(
    const float* __restrict__ inp, const int* __restrict__ indices,
    const int* __restrict__ model_idx, const int* __restrict__ bias_idx,
    const float* __restrict__ W0a, const float* __restrict__ b0a,
    const float* __restrict__ W0b, const float* __restrict__ b0b,
    const float* __restrict__ b1a, const float* __restrict__ b1b,
    const float* __restrict__ b2a, const float* __restrict__ b2b,
    const float* __restrict__ bf, const f16* __restrict__ wsW,
    float* __restrict__ out)
{
  __shared__ __align__(16) char X0[kMB * kRowB];   // 48 KB
  __shared__ __align__(16) char X1[kMB * kRowB];   // 48 KB
  const int d = blockIdx.x;
  const int lg = (d & 7) * 256 + (d >> 3);   // XCD swizzle (2048 % 8 == 0)
  const int c = lg >> 7;                     // 128 blocks per c
  const int n0 = (lg & 127) * kMB;
  const int src = indices[c], m = model_idx[c], bix = bias_idx[c];
  const int tid = threadIdx.x, w = tid >> 6, lane = tid & 63;

  // ---- layer 0 (VALU, f32): real 2->181 + activation, write X0 fp16
  {
    const int r = tid >> 4, sub = tid & 15;
    const float2 xv = *(const float2*)&inp[((size_t)src * kN + n0 + r) * 2];
    const float* w0a0 = W0a + (size_t)(m * 2 + 0) * kH;
    const float* w0a1 = W0a + (size_t)(m * 2 + 1) * kH;
    const float* w0b0 = W0b + (size_t)(m * 2 + 0) * kH;
    const float* w0b1 = W0b + (size_t)(m * 2 + 1) * kH;
    const float* b0av = b0a + (size_t)bix * kH;
    const float* b0bv = b0b + (size_t)bix * kH;
    for (int t = 0; t < 12; ++t) {
      const int o = sub + 16 * t;
      float la = 0.f, lb = 0.f;
      if (o < kH) {
        la = fmaf(xv.y, w0a1[o], fmaf(xv.x, w0a0[o], b0av[o]));
        lb = fmaf(xv.y, w0b1[o], fmaf(xv.x, w0b0[o], b0bv[o]));
      }
      const float amp = __expf(-kS2 * fmaf(la, la, lb * lb));
      const float ph = kOmega * la;
      f16x2 pv = {(f16)(amp * __cosf(ph)), (f16)(amp * __sinf(ph))};
      *(f16x2*)(&X0[0] + swz(r, o * 4)) = pv;
    }
  }
  __syncthreads();
  hidden_gemm(X0, X1, (const f16x8*)(wsW + (size_t)(c * 2 + 0) * kWLayerStride),
              b1a + (size_t)bix * kH * 2, b1b + (size_t)bix * kH * 2, w, lane);
  __syncthreads();
  hidden_gemm(X1, X0, (const f16x8*)(wsW + (size_t)(c * 2 + 1) * kWLayerStride),
              b2a + (size_t)bix * kH * 2, b2b + (size_t)bix * kH * 2, w, lane);
  __syncthreads();
  // ---- final complex 181->3, real part; waves 0..3 own the four 16-row tiles
  if (w < 4) {
    const int kg = lane >> 4, l15 = lane & 15;
    const f16x8* wf = (const f16x8*)(wsW + kWfOff + (size_t)c * kWfStride);
    f32x4 facc = {0.f, 0.f, 0.f, 0.f};
#pragma unroll
    for (int ks = 0; ks < kKS; ++ks) {
      f16x8 a = *(const f16x8*)(&X0[0] + swz(l15 + 16 * w, ks * 64 + kg * 16));
      f16x8 b = wf[(size_t)ks * 64 + lane];
      facc = __builtin_amdgcn_mfma_f32_16x16x32_f16(a, b, facc, 0, 0, 0);
    }
    if (l15 < kOut) {
      const float bfr = bf[(bix * kOut + l15) * 2];
#pragma unroll
      for (int j = 0; j < 4; ++j) {
        const int row = w * 16 + kg * 4 + j;
        out[((size_t)c * kN + n0 + row) * kOut + l15] = facc[j] + bfr;
      }
    }
  }
}

}  // namespace

extern "C" void kernel_launch(void* const* d_in, const int* in_sizes, int n_in,
                              void* d_out, int out_size, void* d_ws, size_t ws_size,
                              hipStream_t stream) {
  const float* inp       = (const float*)d_in[0];
  const int*   indices   = (const int*)  d_in[1];
  const int*   model_idx = (const int*)  d_in[2];
  const int*   bias_idx  = (const int*)  d_in[3];
  const float* W0a = (const float*)d_in[4];
  const float* b0a = (const float*)d_in[5];
  const float* W0b = (const float*)d_in[6];
  const float* b0b = (const float*)d_in[7];
  const float* W1a = (const float*)d_in[8];
  const float* b1a = (const float*)d_in[9];
  const float* W1b = (const float*)d_in[10];
  const float* b1b = (const float*)d_in[11];
  const float* W2a = (const float*)d_in[12];
  const float* b2a = (const float*)d_in[13];
  const float* W2b = (const float*)d_in[14];
  const float* b2b = (const float*)d_in[15];
  const float* Wf  = (const float*)d_in[16];
  const float* bff = (const float*)d_in[17];
  f16*   ws  = (f16*)d_ws;     // needs ~19.1 MB
  float* out = (float*)d_out;

  prep_hidden<<<dim3(kC * 2 * kNT), dim3(768), 0, stream>>>(model_idx, W1a, W1b, W2a, W2b, ws);
  prep_final<<<dim3(kC), dim3(768), 0, stream>>>(model_idx, Wf, ws);
  wire_main<<<dim3(kC * (kN / kMB)), dim3(1024), 0, stream>>>(
      inp, indices, model_idx, bias_idx, W0a, b0a, W0b, b0b,
      b1a, b1b, b2a, b2b, bff, ws, out);
}

// Round 7
// 258.888 us; speedup vs baseline: 5.4905x; 5.4905x over previous
//
#include <hip/hip_runtime.h>

typedef _Float16 f16;
typedef _Float16 f16x2 __attribute__((ext_vector_type(2)));
typedef _Float16 f16x8 __attribute__((ext_vector_type(8)));
typedef float f32x4 __attribute__((ext_vector_type(4)));

namespace {

constexpr int kC = 16, kN = 8192, kH = 181, kOut = 3;
constexpr int kMB = 32;            // rows per block (ping-pong)
constexpr int kKpad = 384;         // 12 ksteps * 32
constexpr int kNT = 48;            // n-tiles of 16 cols (Npad = 768)
constexpr int kKS = 12;            // k-steps of 32
constexpr int kRowB = kKpad * 2;   // 768 bytes per LDS activation row
constexpr float kOmega = 30.f, kS2 = 100.f;

constexpr size_t kWLayerStride = (size_t)kNT * kKS * 64 * 8;  // f16 elems per (c,layer)
constexpr size_t kWfOff = kWLayerStride * kC * 2;             // f16 elems
constexpr size_t kWfStride = (size_t)kKS * 64 * 8;

// XOR-swizzled LDS address (row stride 768B -> bank-degenerate without it).
__device__ __forceinline__ int swz(int row, int colb) {
  return row * kRowB + (colb ^ ((row & 7) << 4));
}

// Quad-lane exchange via DPP (VALU pipe) — keeps the transpose off the DS unit.
__device__ __forceinline__ float dpp_x1(float x) {  // lane ^ 1 within quad
  return __int_as_float(__builtin_amdgcn_mov_dpp(__float_as_int(x), 0xB1, 0xF, 0xF, true));
}
__device__ __forceinline__ float dpp_x2(float x) {  // lane ^ 2 within quad
  return __int_as_float(__builtin_amdgcn_mov_dpp(__float_as_int(x), 0x4E, 0xF, 0xF, true));
}

// 4x4 transpose across the 4-lane comp group (lane bits 0..1).
// In: v_j = C[row_off j][comp = lane&3]. Out: v_j = C[row_off = lane&3][comp j].
__device__ __forceinline__ void xpose4(float& v0, float& v1, float& v2, float& v3, int lane) {
  const bool b0 = lane & 1, b1 = lane & 2;
  float x0 = b0 ? v0 : v1;
  float x1 = b0 ? v2 : v3;
  x0 = dpp_x1(x0);
  x1 = dpp_x1(x1);
  if (b0) { v0 = x0; v2 = x1; } else { v1 = x0; v3 = x1; }
  float y0 = b1 ? v0 : v2;
  float y1 = b1 ? v1 : v3;
  y0 = dpp_x2(y0);
  y1 = dpp_x2(y1);
  if (b1) { v0 = y0; v1 = y1; } else { v2 = y0; v3 = y1; }
}

// ---- prep: pack hidden-layer complex weights into fp16 B-fragment order
// ws[c][L][nt][ks][lane][8]; K rows 2i/2i+1 = (x_re,x_im), N cols 4o+comp.
__global__ __launch_bounds__(768) void prep_hidden(
    const int* __restrict__ model_idx,
    const float* __restrict__ W1a, const float* __restrict__ W1b,
    const float* __restrict__ W2a, const float* __restrict__ W2b,
    f16* __restrict__ ws)
{
  __shared__ float s[kH][2][4][2];   // [i][branch][o_sub][reim]
  const int bid = blockIdx.x;
  const int c  = bid / (2 * kNT);
  const int L  = (bid / kNT) % 2;
  const int nt = bid % kNT;
  const int m  = model_idx[c];
  const float* Wa = (L == 0 ? W1a : W2a) + (size_t)m * kH * kH * 2;
  const float* Wb = (L == 0 ? W1b : W2b) + (size_t)m * kH * kH * 2;
  const int t = threadIdx.x;
  if (t < 2 * kH) {
    const int i = t >> 1, br = t & 1;
    const float* src = (br ? Wb : Wa) + ((size_t)i * kH + nt * 4) * 2;
#pragma unroll
    for (int e = 0; e < 8; ++e) {
      const int osub = e >> 1, reim = e & 1;
      s[i][br][osub][reim] = (nt * 4 + osub < kH) ? src[osub * 2 + reim] : 0.f;
    }
  }
  __syncthreads();
  const int ks = t >> 6, lane = t & 63;
  const int kg = lane >> 4, l15 = lane & 15;
  const int osub = l15 >> 2, comp = l15 & 3, br = comp >> 1;
  const int o = nt * 4 + osub;
  f16x8 v;
#pragma unroll
  for (int j = 0; j < 8; ++j) {
    const int k = ks * 32 + kg * 8 + j;
    float f = 0.f;
    if (k < 2 * kH && o < kH) {
      const int i = k >> 1, kodd = k & 1;
      const int reim = kodd ? (1 - (comp & 1)) : (comp & 1);
      f = s[i][br][osub][reim];
      if (kodd && !(comp & 1)) f = -f;   // -w_im for real-output cols
    }
    v[j] = (f16)f;
  }
  *(f16x8*)&ws[(((size_t)(c * 2 + L) * kNT + nt) * kKS + ks) * 512 + lane * 8] = v;
}

// ---- prep: final layer (real part): col j<3, k=2i -> wf_re, 2i+1 -> -wf_im
__global__ __launch_bounds__(768) void prep_final(
    const int* __restrict__ model_idx, const float* __restrict__ Wf,
    f16* __restrict__ ws)
{
  const int c = blockIdx.x;
  const int m = model_idx[c];
  const int t = threadIdx.x;
  const int ks = t >> 6, lane = t & 63;
  const int kg = lane >> 4, col = lane & 15;
  f16x8 v;
#pragma unroll
  for (int j = 0; j < 8; ++j) {
    const int k = ks * 32 + kg * 8 + j;
    float f = 0.f;
    if (k < 2 * kH && col < kOut) {
      const int i = k >> 1;
      const float* p = &Wf[(((size_t)m * kH + i) * kOut + col) * 2];
      f = (k & 1) ? -p[1] : p[0];
    }
    v[j] = (f16)f;
  }
  *(f16x8*)&ws[kWfOff + ((size_t)c * kKS + ks) * 512 + lane * 8] = v;
}

// ---- one hidden layer: GEMM (32 rows x 768 cols, K=384) + distributed Gabor
// activation, src -> dst buffer. tn=3 grouping (A read once per ks for 3
// n-tiles = minimal LDS traffic). Register budget discipline:
//  - ks-loop unroll capped at 4 (full unroll-12 pipelining pushed demand to
//    132 regs in round 5 -> occupancy collapse),
//  - bias loads AFTER the k-loop (not live across it),
// so demand stays under the 128-VGPR occupancy quantum (m69).
__device__ __forceinline__ void hidden_gemm(
    const char* __restrict__ Xs, char* __restrict__ Xd,
    const f16x8* __restrict__ wl,
    const float* __restrict__ ba, const float* __restrict__ bb,
    int w, int lane)
{
  const int kg = lane >> 4, l15 = lane & 15;
  const int comp = l15 & 3, osub = l15 >> 2;
#pragma unroll 1
  for (int g = 0; g < 4; ++g) {
    const int nt0 = w * 12 + g * 3;
    f32x4 acc[2][3] = {};
#pragma unroll 4
    for (int ks = 0; ks < kKS; ++ks) {
      const f16x8 a0 = *(const f16x8*)(Xs + swz(l15,      ks * 64 + kg * 16));
      const f16x8 a1 = *(const f16x8*)(Xs + swz(l15 + 16, ks * 64 + kg * 16));
#pragma unroll
      for (int tn = 0; tn < 3; ++tn) {
        const f16x8 b = wl[((size_t)(nt0 + tn) * kKS + ks) * 64 + lane];
        acc[0][tn] = __builtin_amdgcn_mfma_f32_16x16x32_f16(a0, b, acc[0][tn], 0, 0, 0);
        acc[1][tn] = __builtin_amdgcn_mfma_f32_16x16x32_f16(a1, b, acc[1][tn], 0, 0, 0);
      }
    }
    // Bias (column property, add pre-transpose) + distributed activation:
    // DPP 4x4 transpose within the comp-group; every lane computes one
    // (row, neuron) Gabor and writes f16x2 straight to Xd.
#pragma unroll
    for (int tn = 0; tn < 3; ++tn) {
      const int q = (nt0 + tn) * 4 + osub;
      float bv = 0.f;
      if (q < kH) bv = ((comp & 2) ? bb : ba)[q * 2 + (comp & 1)];
#pragma unroll
      for (int mt = 0; mt < 2; ++mt) {
        float v0 = acc[mt][tn][0] + bv, v1 = acc[mt][tn][1] + bv;
        float v2 = acc[mt][tn][2] + bv, v3 = acc[mt][tn][3] + bv;
        xpose4(v0, v1, v2, v3, lane);
        // v0..v3 = (la_re, la_im, lb_re, lb_im) at row_off = comp
        const float mag = kS2 * (v0 * v0 + v1 * v1 + v2 * v2 + v3 * v3);
        const float amp = __expf(fmaf(-kOmega, v1, -mag));
        const float ph  = kOmega * v0;
        f16x2 pv = {(f16)(amp * __cosf(ph)), (f16)(amp * __sinf(ph))};
        const int row = mt * 16 + kg * 4 + comp;
        *(f16x2*)(Xd + swz(row, q * 4)) = pv;
      }
    }
  }
}

__global__ __launch_bounds__(256, 4)   // request 4 waves/EU (budget 128)
void wire_main(
    const float* __restrict__ inp, const int* __restrict__ indices,
    const int* __restrict__ model_idx, const int* __restrict__ bias_idx,
    const float* __restrict__ W0a, const float* __restrict__ b0a,
    const float* __restrict__ W0b, const float* __restrict__ b0b,
    const float* __restrict__ b1a, const float* __restrict__ b1b,
    const float* __restrict__ b2a, const float* __restrict__ b2b,
    const float* __restrict__ bf, const f16* __restrict__ wsW,
    float* __restrict__ out)
{
  __shared__ __align__(16) char X0[kMB * kRowB];   // 24 KB
  __shared__ __align__(16) char X1[kMB * kRowB];   // 24 KB
  const int d = blockIdx.x;
  const int lg = (d & 7) * 512 + (d >> 3);   // XCD swizzle (4096 % 8 == 0)
  const int c = lg >> 8;
  const int n0 = (lg & 255) * kMB;
  const int src = indices[c], m = model_idx[c], bix = bias_idx[c];
  const int tid = threadIdx.x, w = tid >> 6, lane = tid & 63;

  // ---- layer 0 (VALU, f32): real 2->181 + activation, write X0 fp16
  {
    const int r = tid >> 3, sub = tid & 7;
    const float2 xv = *(const float2*)&inp[((size_t)src * kN + n0 + r) * 2];
    const float* w0a0 = W0a + (size_t)(m * 2 + 0) * kH;
    const float* w0a1 = W0a + (size_t)(m * 2 + 1) * kH;
    const float* w0b0 = W0b + (size_t)(m * 2 + 0) * kH;
    const float* w0b1 = W0b + (size_t)(m * 2 + 1) * kH;
    const float* b0av = b0a + (size_t)bix * kH;
    const float* b0bv = b0b + (size_t)bix * kH;
    for (int t = 0; t < 24; ++t) {
      const int o = sub + 8 * t;
      float la = 0.f, lb = 0.f;
      if (o < kH) {
        la = fmaf(xv.y, w0a1[o], fmaf(xv.x, w0a0[o], b0av[o]));
        lb = fmaf(xv.y, w0b1[o], fmaf(xv.x, w0b0[o], b0bv[o]));
      }
      const float amp = __expf(-kS2 * fmaf(la, la, lb * lb));
      const float ph = kOmega * la;
      f16x2 pv = {(f16)(amp * __cosf(ph)), (f16)(amp * __sinf(ph))};
      *(f16x2*)(&X0[0] + swz(r, o * 4)) = pv;
    }
  }
  __syncthreads();
  hidden_gemm(X0, X1, (const f16x8*)(wsW + (size_t)(c * 2 + 0) * kWLayerStride),
              b1a + (size_t)bix * kH * 2, b1b + (size_t)bix * kH * 2, w, lane);
  __syncthreads();
  hidden_gemm(X1, X0, (const f16x8*)(wsW + (size_t)(c * 2 + 1) * kWLayerStride),
              b2a + (size_t)bix * kH * 2, b2b + (size_t)bix * kH * 2, w, lane);
  __syncthreads();
  // ---- final complex 181->3, real part; waves 0,1 own the two 16-row tiles
  if (w < 2) {
    const int kg = lane >> 4, l15 = lane & 15;
    const f16x8* wf = (const f16x8*)(wsW + kWfOff + (size_t)c * kWfStride);
    f32x4 facc = {0.f, 0.f, 0.f, 0.f};
#pragma unroll
    for (int ks = 0; ks < kKS; ++ks) {
      f16x8 a = *(const f16x8*)(&X0[0] + swz(l15 + 16 * w, ks * 64 + kg * 16));
      f16x8 b = wf[(size_t)ks * 64 + lane];
      facc = __builtin_amdgcn_mfma_f32_16x16x32_f16(a, b, facc, 0, 0, 0);
    }
    if (l15 < kOut) {
      const float bfr = bf[(bix * kOut + l15) * 2];
#pragma unroll
      for (int j = 0; j < 4; ++j) {
        const int row = w * 16 + kg * 4 + j;
        out[((size_t)c * kN + n0 + row) * kOut + l15] = facc[j] + bfr;
      }
    }
  }
}

}  // namespace

extern "C" void kernel_launch(void* const* d_in, const int* in_sizes, int n_in,
                              void* d_out, int out_size, void* d_ws, size_t ws_size,
                              hipStream_t stream) {
  const float* inp       = (const float*)d_in[0];
  const int*   indices   = (const int*)  d_in[1];
  const int*   model_idx = (const int*)  d_in[2];
  const int*   bias_idx  = (const int*)  d_in[3];
  const float* W0a = (const float*)d_in[4];
  const float* b0a = (const float*)d_in[5];
  const float* W0b = (const float*)d_in[6];
  const float* b0b = (const float*)d_in[7];
  const float* W1a = (const float*)d_in[8];
  const float* b1a = (const float*)d_in[9];
  const float* W1b = (const float*)d_in[10];
  const float* b1b = (const float*)d_in[11];
  const float* W2a = (const float*)d_in[12];
  const float* b2a = (const float*)d_in[13];
  const float* W2b = (const float*)d_in[14];
  const float* b2b = (const float*)d_in[15];
  const float* Wf  = (const float*)d_in[16];
  const float* bff = (const float*)d_in[17];
  f16*   ws  = (f16*)d_ws;     // needs ~19.1 MB
  float* out = (float*)d_out;

  prep_hidden<<<dim3(kC * 2 * kNT), dim3(768), 0, stream>>>(model_idx, W1a, W1b, W2a, W2b, ws);
  prep_final<<<dim3(kC), dim3(768), 0, stream>>>(model_idx, Wf, ws);
  wire_main<<<dim3(kC * (kN / kMB)), dim3(256), 0, stream>>>(
      inp, indices, model_idx, bias_idx, W0a, b0a, W0b, b0b,
      b1a, b1b, b2a, b2b, bff, ws, out);
}

// Round 8
// 246.515 us; speedup vs baseline: 5.7660x; 1.0502x over previous
//
#include <hip/hip_runtime.h>

typedef _Float16 f16;
typedef _Float16 f16x2 __attribute__((ext_vector_type(2)));
typedef _Float16 f16x8 __attribute__((ext_vector_type(8)));
typedef float f32x4 __attribute__((ext_vector_type(4)));

namespace {

constexpr int kC = 16, kN = 8192, kH = 181, kOut = 3;
constexpr int kMB = 32;            // points per block (ping-pong)
constexpr int kKpad = 384;         // 12 ksteps * 32
constexpr int kNT = 48;            // tiles of 16 output-comps (4 neurons each)
constexpr int kKS = 12;            // k-steps of 32
constexpr int kRowB = kKpad * 2;   // 768 bytes per LDS activation row
constexpr float kOmega = 30.f, kS2 = 100.f;

constexpr size_t kWLayerStride = (size_t)kNT * kKS * 64 * 8;  // f16 elems per (c,layer)
constexpr size_t kWfOff = kWLayerStride * kC * 2;             // f16 elems
constexpr size_t kWfStride = (size_t)kKS * 64 * 8;

// XOR-swizzled LDS address (row stride 768B -> bank-degenerate without it).
__device__ __forceinline__ int swz(int row, int colb) {
  return row * kRowB + (colb ^ ((row & 7) << 4));
}

// ---- prep: pack hidden-layer complex weights into fp16 fragment order
// ws[c][L][nt][ks][lane][8]; K rows 2i/2i+1 = (x_re,x_im), 16-wide tile dim =
// 4o+comp. Used as the MFMA *A* operand (C^T formulation): lane&15 = output
// comp row, k = ks*32 + (lane>>4)*8 + j. Byte-identical to the old B packing.
__global__ __launch_bounds__(768) void prep_hidden(
    const int* __restrict__ model_idx,
    const float* __restrict__ W1a, const float* __restrict__ W1b,
    const float* __restrict__ W2a, const float* __restrict__ W2b,
    f16* __restrict__ ws)
{
  __shared__ float s[kH][2][4][2];   // [i][branch][o_sub][reim]
  const int bid = blockIdx.x;
  const int c  = bid / (2 * kNT);
  const int L  = (bid / kNT) % 2;
  const int nt = bid % kNT;
  const int m  = model_idx[c];
  const float* Wa = (L == 0 ? W1a : W2a) + (size_t)m * kH * kH * 2;
  const float* Wb = (L == 0 ? W1b : W2b) + (size_t)m * kH * kH * 2;
  const int t = threadIdx.x;
  if (t < 2 * kH) {
    const int i = t >> 1, br = t & 1;
    const float* src = (br ? Wb : Wa) + ((size_t)i * kH + nt * 4) * 2;
#pragma unroll
    for (int e = 0; e < 8; ++e) {
      const int osub = e >> 1, reim = e & 1;
      s[i][br][osub][reim] = (nt * 4 + osub < kH) ? src[osub * 2 + reim] : 0.f;
    }
  }
  __syncthreads();
  const int ks = t >> 6, lane = t & 63;
  const int kg = lane >> 4, l15 = lane & 15;
  const int osub = l15 >> 2, comp = l15 & 3, br = comp >> 1;
  const int o = nt * 4 + osub;
  f16x8 v;
#pragma unroll
  for (int j = 0; j < 8; ++j) {
    const int k = ks * 32 + kg * 8 + j;
    float f = 0.f;
    if (k < 2 * kH && o < kH) {
      const int i = k >> 1, kodd = k & 1;
      const int reim = kodd ? (1 - (comp & 1)) : (comp & 1);
      f = s[i][br][osub][reim];
      if (kodd && !(comp & 1)) f = -f;   // -w_im for real-output rows
    }
    v[j] = (f16)f;
  }
  *(f16x8*)&ws[(((size_t)(c * 2 + L) * kNT + nt) * kKS + ks) * 512 + lane * 8] = v;
}

// ---- prep: final layer (real part): col j<3, k=2i -> wf_re, 2i+1 -> -wf_im
__global__ __launch_bounds__(768) void prep_final(
    const int* __restrict__ model_idx, const float* __restrict__ Wf,
    f16* __restrict__ ws)
{
  const int c = blockIdx.x;
  const int m = model_idx[c];
  const int t = threadIdx.x;
  const int ks = t >> 6, lane = t & 63;
  const int kg = lane >> 4, col = lane & 15;
  f16x8 v;
#pragma unroll
  for (int j = 0; j < 8; ++j) {
    const int k = ks * 32 + kg * 8 + j;
    float f = 0.f;
    if (k < 2 * kH && col < kOut) {
      const int i = k >> 1;
      const float* p = &Wf[(((size_t)m * kH + i) * kOut + col) * 2];
      f = (k & 1) ? -p[1] : p[0];
    }
    v[j] = (f16)f;
  }
  *(f16x8*)&ws[kWfOff + ((size_t)c * kKS + ks) * 512 + lane * 8] = v;
}

// ---- one hidden layer, C^T formulation: C[i=out comp][j=point].
// A = weights (global, streamed once per M-tile), B = X (LDS, ALL 12 ks x
// 2 point-tiles held in 96 VGPRs across the whole M loop). Each lane's 4 acc
// regs = the 4 comps (la_re, la_im, lb_re, lb_im) of one (neuron, point) ->
// activation needs NO cross-lane transpose at all.
__device__ __forceinline__ void hidden_gemm(
    const char* __restrict__ Xs, char* __restrict__ Xd,
    const f16x8* __restrict__ wl,
    const float* __restrict__ ba, const float* __restrict__ bb,
    int w, int lane)
{
  const int kg = lane >> 4, l15 = lane & 15;
  // Hold B (activations) for both point-tiles, full K: 24 x f16x8 = 96 VGPR.
  f16x8 B0[kKS], B1[kKS];
#pragma unroll
  for (int ks = 0; ks < kKS; ++ks) {
    B0[ks] = *(const f16x8*)(Xs + swz(l15,      ks * 64 + kg * 16));
    B1[ks] = *(const f16x8*)(Xs + swz(l15 + 16, ks * 64 + kg * 16));
  }
#pragma unroll 1
  for (int mi = 0; mi < 12; ++mi) {
    const int nt = w * 12 + mi;
    const int q = nt * 4 + kg;           // this lane's neuron
    const f16x8* ap = wl + (size_t)nt * kKS * 64 + lane;
    // bias folded into acc init: regs = (la_re, la_im, lb_re, lb_im)
    f32x4 binit = {0.f, 0.f, 0.f, 0.f};
    if (q < kH) {
      const float2 bav = *(const float2*)&ba[q * 2];
      const float2 bbv = *(const float2*)&bb[q * 2];
      binit = f32x4{bav.x, bav.y, bbv.x, bbv.y};
    }
    f32x4 acc0 = binit, acc1 = binit;
#pragma unroll
    for (int ks = 0; ks < kKS; ++ks) {
      const f16x8 a = ap[ks * 64];       // weight frag from L2
      acc0 = __builtin_amdgcn_mfma_f32_16x16x32_f16(a, B0[ks], acc0, 0, 0, 0);
      acc1 = __builtin_amdgcn_mfma_f32_16x16x32_f16(a, B1[ks], acc1, 0, 0, 0);
    }
    // Gabor activation straight from registers (no transpose).
#pragma unroll
    for (int pt = 0; pt < 2; ++pt) {
      const f32x4 v = pt ? acc1 : acc0;
      const float mag = kS2 * (v[0]*v[0] + v[1]*v[1] + v[2]*v[2] + v[3]*v[3]);
      const float amp = __expf(fmaf(-kOmega, v[1], -mag));
      const float ph  = kOmega * v[0];
      f16x2 pv = {(f16)(amp * __cosf(ph)), (f16)(amp * __sinf(ph))};
      *(f16x2*)(Xd + swz(l15 + 16 * pt, q * 4)) = pv;
    }
  }
}

__global__ __launch_bounds__(256, 3)   // 3 blocks/CU (LDS-limited) -> VGPR cap 170
void wire_main(
    const float* __restrict__ inp, const int* __restrict__ indices,
    const int* __restrict__ model_idx, const int* __restrict__ bias_idx,
    const float* __restrict__ W0a, const float* __restrict__ b0a,
    const float* __restrict__ W0b, const float* __restrict__ b0b,
    const float* __restrict__ b1a, const float* __restrict__ b1b,
    const float* __restrict__ b2a, const float* __restrict__ b2b,
    const float* __restrict__ bf, const f16* __restrict__ wsW,
    float* __restrict__ out)
{
  __shared__ __align__(16) char X0[kMB * kRowB];   // 24 KB
  __shared__ __align__(16) char X1[kMB * kRowB];   // 24 KB
  const int d = blockIdx.x;
  const int lg = (d & 7) * 512 + (d >> 3);   // XCD swizzle (4096 % 8 == 0)
  const int c = lg >> 8;
  const int n0 = (lg & 255) * kMB;
  const int src = indices[c], m = model_idx[c], bix = bias_idx[c];
  const int tid = threadIdx.x, w = tid >> 6, lane = tid & 63;

  // ---- layer 0 (VALU, f32): real 2->181 + activation, write X0 fp16
  {
    const int r = tid >> 3, sub = tid & 7;
    const float2 xv = *(const float2*)&inp[((size_t)src * kN + n0 + r) * 2];
    const float* w0a0 = W0a + (size_t)(m * 2 + 0) * kH;
    const float* w0a1 = W0a + (size_t)(m * 2 + 1) * kH;
    const float* w0b0 = W0b + (size_t)(m * 2 + 0) * kH;
    const float* w0b1 = W0b + (size_t)(m * 2 + 1) * kH;
    const float* b0av = b0a + (size_t)bix * kH;
    const float* b0bv = b0b + (size_t)bix * kH;
    for (int t = 0; t < 24; ++t) {
      const int o = sub + 8 * t;
      float la = 0.f, lb = 0.f;
      if (o < kH) {
        la = fmaf(xv.y, w0a1[o], fmaf(xv.x, w0a0[o], b0av[o]));
        lb = fmaf(xv.y, w0b1[o], fmaf(xv.x, w0b0[o], b0bv[o]));
      }
      const float amp = __expf(-kS2 * fmaf(la, la, lb * lb));
      const float ph = kOmega * la;
      f16x2 pv = {(f16)(amp * __cosf(ph)), (f16)(amp * __sinf(ph))};
      *(f16x2*)(&X0[0] + swz(r, o * 4)) = pv;
    }
  }
  __syncthreads();
  hidden_gemm(X0, X1, (const f16x8*)(wsW + (size_t)(c * 2 + 0) * kWLayerStride),
              b1a + (size_t)bix * kH * 2, b1b + (size_t)bix * kH * 2, w, lane);
  __syncthreads();
  hidden_gemm(X1, X0, (const f16x8*)(wsW + (size_t)(c * 2 + 1) * kWLayerStride),
              b2a + (size_t)bix * kH * 2, b2b + (size_t)bix * kH * 2, w, lane);
  __syncthreads();
  // ---- final complex 181->3, real part; waves 0,1 own the two 16-row tiles
  if (w < 2) {
    const int kg = lane >> 4, l15 = lane & 15;
    const f16x8* wf = (const f16x8*)(wsW + kWfOff + (size_t)c * kWfStride);
    f32x4 facc = {0.f, 0.f, 0.f, 0.f};
#pragma unroll
    for (int ks = 0; ks < kKS; ++ks) {
      f16x8 a = *(const f16x8*)(&X0[0] + swz(l15 + 16 * w, ks * 64 + kg * 16));
      f16x8 b = wf[(size_t)ks * 64 + lane];
      facc = __builtin_amdgcn_mfma_f32_16x16x32_f16(a, b, facc, 0, 0, 0);
    }
    if (l15 < kOut) {
      const float bfr = bf[(bix * kOut + l15) * 2];
#pragma unroll
      for (int j = 0; j < 4; ++j) {
        const int row = w * 16 + kg * 4 + j;
        out[((size_t)c * kN + n0 + row) * kOut + l15] = facc[j] + bfr;
      }
    }
  }
}

}  // namespace

extern "C" void kernel_launch(void* const* d_in, const int* in_sizes, int n_in,
                              void* d_out, int out_size, void* d_ws, size_t ws_size,
                              hipStream_t stream) {
  const float* inp       = (const float*)d_in[0];
  const int*   indices   = (const int*)  d_in[1];
  const int*   model_idx = (const int*)  d_in[2];
  const int*   bias_idx  = (const int*)  d_in[3];
  const float* W0a = (const float*)d_in[4];
  const float* b0a = (const float*)d_in[5];
  const float* W0b = (const float*)d_in[6];
  const float* b0b = (const float*)d_in[7];
  const float* W1a = (const float*)d_in[8];
  const float* b1a = (const float*)d_in[9];
  const float* W1b = (const float*)d_in[10];
  const float* b1b = (const float*)d_in[11];
  const float* W2a = (const float*)d_in[12];
  const float* b2a = (const float*)d_in[13];
  const float* W2b = (const float*)d_in[14];
  const float* b2b = (const float*)d_in[15];
  const float* Wf  = (const float*)d_in[16];
  const float* bff = (const float*)d_in[17];
  f16*   ws  = (f16*)d_ws;     // needs ~19.1 MB
  float* out = (float*)d_out;

  prep_hidden<<<dim3(kC * 2 * kNT), dim3(768), 0, stream>>>(model_idx, W1a, W1b, W2a, W2b, ws);
  prep_final<<<dim3(kC), dim3(768), 0, stream>>>(model_idx, Wf, ws);
  wire_main<<<dim3(kC * (kN / kMB)), dim3(256), 0, stream>>>(
      inp, indices, model_idx, bias_idx, W0a, b0a, W0b, b0b,
      b1a, b1b, b2a, b2b, bff, ws, out);
}

// Round 9
// 219.130 us; speedup vs baseline: 6.4866x; 1.1250x over previous
//
#include <hip/hip_runtime.h>

typedef _Float16 f16;
typedef _Float16 f16x2 __attribute__((ext_vector_type(2)));
typedef _Float16 f16x8 __attribute__((ext_vector_type(8)));
typedef float f32x4 __attribute__((ext_vector_type(4)));

namespace {

constexpr int kC = 16, kN = 8192, kH = 181, kOut = 3;
constexpr int kMB = 64;            // points per block (in-place, 4-tile reg hold)
constexpr int kKpad = 384;         // 12 ksteps * 32
constexpr int kNT = 48;            // tiles of 16 output-comps (4 neurons each)
constexpr int kKS = 12;            // k-steps of 32
constexpr int kRowB = 784;         // 768 data bytes + 16B pad: 784/4=196==4 mod 32
                                   // -> rows spread banks, XOR swizzle deleted
constexpr float kOmega = 30.f, kS2 = 100.f;

constexpr size_t kWLayerStride = (size_t)kNT * kKS * 64 * 8;  // f16 elems per (c,layer)
constexpr size_t kWfOff = kWLayerStride * kC * 2;             // f16 elems
constexpr size_t kWfStride = (size_t)kKS * 64 * 8;

__device__ __forceinline__ int xadr(int row, int colb) { return row * kRowB + colb; }

// ---- prep: pack hidden-layer complex weights into fp16 fragment order
// ws[c][L][nt][ks][lane][8]; K rows 2i/2i+1 = (x_re,x_im), 16-wide tile dim =
// 4o+comp. Used as the MFMA *A* operand (C^T formulation).
__global__ __launch_bounds__(768) void prep_hidden(
    const int* __restrict__ model_idx,
    const float* __restrict__ W1a, const float* __restrict__ W1b,
    const float* __restrict__ W2a, const float* __restrict__ W2b,
    f16* __restrict__ ws)
{
  __shared__ float s[kH][2][4][2];   // [i][branch][o_sub][reim]
  const int bid = blockIdx.x;
  const int c  = bid / (2 * kNT);
  const int L  = (bid / kNT) % 2;
  const int nt = bid % kNT;
  const int m  = model_idx[c];
  const float* Wa = (L == 0 ? W1a : W2a) + (size_t)m * kH * kH * 2;
  const float* Wb = (L == 0 ? W1b : W2b) + (size_t)m * kH * kH * 2;
  const int t = threadIdx.x;
  if (t < 2 * kH) {
    const int i = t >> 1, br = t & 1;
    const float* src = (br ? Wb : Wa) + ((size_t)i * kH + nt * 4) * 2;
#pragma unroll
    for (int e = 0; e < 8; ++e) {
      const int osub = e >> 1, reim = e & 1;
      s[i][br][osub][reim] = (nt * 4 + osub < kH) ? src[osub * 2 + reim] : 0.f;
    }
  }
  __syncthreads();
  const int ks = t >> 6, lane = t & 63;
  const int kg = lane >> 4, l15 = lane & 15;
  const int osub = l15 >> 2, comp = l15 & 3, br = comp >> 1;
  const int o = nt * 4 + osub;
  f16x8 v;
#pragma unroll
  for (int j = 0; j < 8; ++j) {
    const int k = ks * 32 + kg * 8 + j;
    float f = 0.f;
    if (k < 2 * kH && o < kH) {
      const int i = k >> 1, kodd = k & 1;
      const int reim = kodd ? (1 - (comp & 1)) : (comp & 1);
      f = s[i][br][osub][reim];
      if (kodd && !(comp & 1)) f = -f;   // -w_im for real-output rows
    }
    v[j] = (f16)f;
  }
  *(f16x8*)&ws[(((size_t)(c * 2 + L) * kNT + nt) * kKS + ks) * 512 + lane * 8] = v;
}

// ---- prep: final layer (real part): col j<3, k=2i -> wf_re, 2i+1 -> -wf_im
__global__ __launch_bounds__(768) void prep_final(
    const int* __restrict__ model_idx, const float* __restrict__ Wf,
    f16* __restrict__ ws)
{
  const int c = blockIdx.x;
  const int m = model_idx[c];
  const int t = threadIdx.x;
  const int ks = t >> 6, lane = t & 63;
  const int kg = lane >> 4, col = lane & 15;
  f16x8 v;
#pragma unroll
  for (int j = 0; j < 8; ++j) {
    const int k = ks * 32 + kg * 8 + j;
    float f = 0.f;
    if (k < 2 * kH && col < kOut) {
      const int i = k >> 1;
      const float* p = &Wf[(((size_t)m * kH + i) * kOut + col) * 2];
      f = (k & 1) ? -p[1] : p[0];
    }
    v[j] = (f16)v[j], v[j] = (f16)f;
  }
  *(f16x8*)&ws[kWfOff + ((size_t)c * kKS + ks) * 512 + lane * 8] = v;
}

// ---- one hidden layer, IN PLACE, C^T formulation.
// Step 1: every wave loads the ENTIRE X for its lanes' points into registers
//         (B-hold: 4 pt-tiles x 12 ks = 48 f16x8 = 192 VGPR).
// Step 2: barrier (X fully consumed block-wide -> overwrite is race-free).
// Step 3: M-loop over this wave's 12 comp-tiles: stream weight frags (A) from
//         L2 (each feeds 4 MFMAs), accumulate, bias + Gabor activation per
//         lane (acc = the 4 comps of one (neuron, point)), write back to X.
// ks loops are FULLY unrolled: partial unroll leaves B[pt][ks] runtime-indexed
// -> scratch (rule #20; rounds 3/4/6 scratch disasters).
__device__ __forceinline__ void hidden_gemm(
    char* __restrict__ X, const f16x8* __restrict__ wl,
    const float* __restrict__ ba, const float* __restrict__ bb,
    int w, int lane)
{
  const int kg = lane >> 4, l15 = lane & 15;
  f16x8 B[4][kKS];
#pragma unroll
  for (int pt = 0; pt < 4; ++pt)
#pragma unroll
    for (int ks = 0; ks < kKS; ++ks)
      B[pt][ks] = *(const f16x8*)(X + xadr(l15 + 16 * pt, ks * 64 + kg * 16));
  __syncthreads();   // all waves hold X in regs; X may now be overwritten

#pragma unroll 1
  for (int mi = 0; mi < 12; ++mi) {
    const int nt = w * 12 + mi;
    const int q = nt * 4 + kg;           // this lane's neuron
    const f16x8* ap = wl + (size_t)nt * (kKS * 64) + lane;
    f32x4 acc[4] = {};
#pragma unroll
    for (int ks = 0; ks < kKS; ++ks) {
      const f16x8 a = ap[ks * 64];       // weight frag from L2, feeds 4 MFMAs
      acc[0] = __builtin_amdgcn_mfma_f32_16x16x32_f16(a, B[0][ks], acc[0], 0, 0, 0);
      acc[1] = __builtin_amdgcn_mfma_f32_16x16x32_f16(a, B[1][ks], acc[1], 0, 0, 0);
      acc[2] = __builtin_amdgcn_mfma_f32_16x16x32_f16(a, B[2][ks], acc[2], 0, 0, 0);
      acc[3] = __builtin_amdgcn_mfma_f32_16x16x32_f16(a, B[3][ks], acc[3], 0, 0, 0);
    }
    float br_ = 0.f, bi_ = 0.f, cr_ = 0.f, ci_ = 0.f;
    if (q < kH) {
      const float2 bav = *(const float2*)&ba[q * 2];
      const float2 bbv = *(const float2*)&bb[q * 2];
      br_ = bav.x; bi_ = bav.y; cr_ = bbv.x; ci_ = bbv.y;
    }
    // Gabor activation straight from registers (no cross-lane transpose).
#pragma unroll
    for (int pt = 0; pt < 4; ++pt) {
      const float v0 = acc[pt][0] + br_, v1 = acc[pt][1] + bi_;
      const float v2 = acc[pt][2] + cr_, v3 = acc[pt][3] + ci_;
      const float mag = kS2 * (v0 * v0 + v1 * v1 + v2 * v2 + v3 * v3);
      const float amp = __expf(fmaf(-kOmega, v1, -mag));
      const float ph  = kOmega * v0;
      f16x2 pv = {(f16)(amp * __cosf(ph)), (f16)(amp * __sinf(ph))};
      *(f16x2*)(X + xadr(l15 + 16 * pt, q * 4)) = pv;
    }
  }
}

__global__ __launch_bounds__(256, 2)   // budget 256: B-hold 192 + ~50 working set
void wire_main(
    const float* __restrict__ inp, const int* __restrict__ indices,
    const int* __restrict__ model_idx, const int* __restrict__ bias_idx,
    const float* __restrict__ W0a, const float* __restrict__ b0a,
    const float* __restrict__ W0b, const float* __restrict__ b0b,
    const float* __restrict__ b1a, const float* __restrict__ b1b,
    const float* __restrict__ b2a, const float* __restrict__ b2b,
    const float* __restrict__ bf, const f16* __restrict__ wsW,
    float* __restrict__ out)
{
  __shared__ __align__(16) char X[kMB * kRowB];   // 49 KB single buffer
  const int d = blockIdx.x;
  const int lg = (d & 7) * 256 + (d >> 3);   // XCD swizzle (2048 % 8 == 0)
  const int c = lg >> 7;                     // 128 blocks per c
  const int n0 = (lg & 127) * kMB;
  const int src = indices[c], m = model_idx[c], bix = bias_idx[c];
  const int tid = threadIdx.x, w = tid >> 6, lane = tid & 63;

  // ---- layer 0 (VALU, f32): real 2->181 + activation, write X fp16
  {
    const int r = tid >> 2, sub = tid & 3;
    const float2 xv = *(const float2*)&inp[((size_t)src * kN + n0 + r) * 2];
    const float* w0a0 = W0a + (size_t)(m * 2 + 0) * kH;
    const float* w0a1 = W0a + (size_t)(m * 2 + 1) * kH;
    const float* w0b0 = W0b + (size_t)(m * 2 + 0) * kH;
    const float* w0b1 = W0b + (size_t)(m * 2 + 1) * kH;
    const float* b0av = b0a + (size_t)bix * kH;
    const float* b0bv = b0b + (size_t)bix * kH;
    for (int t = 0; t < 48; ++t) {
      const int o = sub + 4 * t;
      float la = 0.f, lb = 0.f;
      if (o < kH) {
        la = fmaf(xv.y, w0a1[o], fmaf(xv.x, w0a0[o], b0av[o]));
        lb = fmaf(xv.y, w0b1[o], fmaf(xv.x, w0b0[o], b0bv[o]));
      }
      const float amp = __expf(-kS2 * fmaf(la, la, lb * lb));
      const float ph = kOmega * la;
      f16x2 pv = {(f16)(amp * __cosf(ph)), (f16)(amp * __sinf(ph))};
      *(f16x2*)(&X[0] + xadr(r, o * 4)) = pv;
    }
  }
  __syncthreads();
  hidden_gemm(X, (const f16x8*)(wsW + (size_t)(c * 2 + 0) * kWLayerStride),
              b1a + (size_t)bix * kH * 2, b1b + (size_t)bix * kH * 2, w, lane);
  __syncthreads();
  hidden_gemm(X, (const f16x8*)(wsW + (size_t)(c * 2 + 1) * kWLayerStride),
              b2a + (size_t)bix * kH * 2, b2b + (size_t)bix * kH * 2, w, lane);
  __syncthreads();
  // ---- final complex 181->3, real part; wave w owns point-tile w
  {
    const int kg = lane >> 4, l15 = lane & 15;
    const f16x8* wf = (const f16x8*)(wsW + kWfOff + (size_t)c * kWfStride);
    f32x4 facc = {0.f, 0.f, 0.f, 0.f};
#pragma unroll
    for (int ks = 0; ks < kKS; ++ks) {
      f16x8 a = *(const f16x8*)(&X[0] + xadr(l15 + 16 * w, ks * 64 + kg * 16));
      f16x8 b = wf[(size_t)ks * 64 + lane];
      facc = __builtin_amdgcn_mfma_f32_16x16x32_f16(a, b, facc, 0, 0, 0);
    }
    if (l15 < kOut) {
      const float bfr = bf[(bix * kOut + l15) * 2];
#pragma unroll
      for (int j = 0; j < 4; ++j) {
        const int row = w * 16 + kg * 4 + j;
        out[((size_t)c * kN + n0 + row) * kOut + l15] = facc[j] + bfr;
      }
    }
  }
}

}  // namespace

extern "C" void kernel_launch(void* const* d_in, const int* in_sizes, int n_in,
                              void* d_out, int out_size, void* d_ws, size_t ws_size,
                              hipStream_t stream) {
  const float* inp       = (const float*)d_in[0];
  const int*   indices   = (const int*)  d_in[1];
  const int*   model_idx = (const int*)  d_in[2];
  const int*   bias_idx  = (const int*)  d_in[3];
  const float* W0a = (const float*)d_in[4];
  const float* b0a = (const float*)d_in[5];
  const float* W0b = (const float*)d_in[6];
  const float* b0b = (const float*)d_in[7];
  const float* W1a = (const float*)d_in[8];
  const float* b1a = (const float*)d_in[9];
  const float* W1b = (const float*)d_in[10];
  const float* b1b = (const float*)d_in[11];
  const float* W2a = (const float*)d_in[12];
  const float* b2a = (const float*)d_in[13];
  const float* W2b = (const float*)d_in[14];
  const float* b2b = (const float*)d_in[15];
  const float* Wf  = (const float*)d_in[16];
  const float* bff = (const float*)d_in[17];
  f16*   ws  = (f16*)d_ws;     // needs ~19.1 MB
  float* out = (float*)d_out;

  prep_hidden<<<dim3(kC * 2 * kNT), dim3(768), 0, stream>>>(model_idx, W1a, W1b, W2a, W2b, ws);
  prep_final<<<dim3(kC), dim3(768), 0, stream>>>(model_idx, Wf, ws);
  wire_main<<<dim3(kC * (kN / kMB)), dim3(256), 0, stream>>>(
      inp, indices, model_idx, bias_idx, W0a, b0a, W0b, b0b,
      b1a, b1b, b2a, b2b, bff, ws, out);
}